// Round 2
// baseline (10224.989 us; speedup 1.0000x reference)
//
#include <hip/hip_runtime.h>
#include <stdint.h>
#include <stddef.h>

// Persistent 2-layer LSTM decoder, B=1024, H=256, T=512.
//
// R6: antiphase co-residency. R5 showed the step is latency-bound, not
// work-bound: per-SIMD busy ~6-7k cyc of a 22.9k-cyc step (MfmaUtil 9.7%,
// VALUBusy 21%, 1 wave/SIMD) — ~16k cyc/step of barrier + h-broadcast +
// drain stalls that nothing can cover at occupancy 1.
//  - 32 groups x 16 WGs x 256 threads (512 blocks, 2 blocks/CU). Each group
//    owns 32 chains; the two blocks on a CU belong to DIFFERENT groups
//    (slot i and slot i+32 of an XCD differ in group by construction), and
//    different groups' time loops free-run independently => their stalls are
//    uncorrelated, so one wave's barrier/vmcnt wait is covered by the other
//    wave's MFMA/VALU issue on the same SIMD.
//  - Per-wave work halves (M=32: 68 MFMAs/wave/step); weights/thread
//    unchanged; retained-h1 frags halve to 8 x half8. ~230 VGPR => two
//    256-VGPR waves/SIMD fit exactly. LDS 31.7KB/block, 2 blocks/CU.
//  - Data path unchanged from R5: SB0 LDS staging via global_load_lds,
//    h1 register retention across barrier2, single L2 h-buffer per
//    group/layer, XCD-local groups (HW_REG_XCC_ID + slot claim),
//    write-through stores + buffer_inv sc0 acquire, RMW group barrier.
//
// h-buffer layout (per group, per layer): chunked f16
//   f16_index = (c*32 + m)*8 + e   where c = k/8 (0..31), m = row (0..31),
//   e = k%8; an MFMA A-fragment (8 consecutive k for one m) is one 16B
//   chunk, chunk c is a contiguous 512B block (=> linear global_load_lds).

#define NGROUP 32
#define GWG    16
#define NTHR   256
#define TSTEPS 512

typedef _Float16 half8 __attribute__((ext_vector_type(8)));
typedef float    f32x4 __attribute__((ext_vector_type(4)));

#define OUT_ELEMS   33554432   // 1024*512*64
#define HF_ELEMS    524288     // 2*1024*256
#define HBUF_ELEMS  8192       // 32*256 (f16) per layer
#define GROUP_WS_BYTES 32768   // 2 layers * 16KB
#define WS_SLOT_OFF 4096       // per-XCD slot-claim counters
#define WS_HBUF_OFF 8192
#define WS_NEEDED   (WS_HBUF_OFF + NGROUP * GROUP_WS_BYTES)

__device__ __forceinline__ float sigm(float x)   { return 1.0f / (1.0f + __expf(-x)); }
__device__ __forceinline__ float tanh_f(float x) { return 1.0f - 2.0f / (__expf(2.0f * x) + 1.0f); }

// XCD-local group barrier. All 16 member WGs are on one XCD by construction
// (groups derived from HW_REG_XCC_ID). Stores are in the XCD L2 when each
// wave's pre-s_barrier s_waitcnt vmcnt(0) retires (write-through L1).
// Arrive/poll are real RMWs at the L2 (zz = opaque zero defeats the
// atomicrmw-add-0 -> load fold). Acquire = L1 invalidate only.
__device__ __forceinline__ void group_barrier(int* ctr, int* phase, int zz) {
  __syncthreads();
  if (threadIdx.x == 0) {
    __hip_atomic_fetch_add(ctr, 1, __ATOMIC_RELEASE, __HIP_MEMORY_SCOPE_WORKGROUP);
    const int target = GWG * (++(*phase));
    while (__hip_atomic_fetch_add(ctr, zz, __ATOMIC_RELAXED, __HIP_MEMORY_SCOPE_WORKGROUP) < target)
      __builtin_amdgcn_s_sleep(1);
    asm volatile("buffer_inv sc0" ::: "memory");   // L1-only invalidate (gfx940+)
  }
  __syncthreads();
}

// 16B A-fragment plain load from a chunked h-buffer in L2.
__device__ __forceinline__ half8 ld_frag(const _Float16* buf, int idx16) {
  return *(const half8*)(buf + (size_t)idx16 * 8);
}

// 16KB linear global->LDS copy, zero VGPR destination. 4 insts/wave, wave wv
// handles 1KB blocks {i*4+wv}. LDS dest = wave-uniform base + lane*16.
__device__ __forceinline__ void stage16k(const void* src, void* lds_dst, int tid) {
  const int wv = tid >> 6;
  const int ln = tid & 63;
  const char* s = (const char*)src + ln * 16;
  char* d = (char*)lds_dst;
  #pragma unroll
  for (int i = 0; i < 4; ++i) {
    const int off = (i * 4 + wv) * 1024;
    __builtin_amdgcn_global_load_lds(
        (const __attribute__((address_space(1))) void*)(s + off),
        (__attribute__((address_space(3))) void*)(d + off),
        16, 0, 0);
  }
}

// Packed f16x2 plain store of (col u, col u+1) for row mh. Even-u lanes only.
__device__ __forceinline__ void store_h_pair(_Float16* hw, int w, int u, int mh,
                                             float lo, float hi) {
  union { _Float16 h[2]; uint32_t u32; } pk;
  pk.h[0] = (_Float16)lo; pk.h[1] = (_Float16)hi;
  const int c = w * 2 + (u >> 3);
  *((uint32_t*)hw + (size_t)(c * 32 + mh) * 4 + ((u & 7) >> 1)) = pk.u32;
}

__global__ __launch_bounds__(NTHR, 2)
void decoder_kernel(const float* __restrict__ h0in, const float* __restrict__ c0in,
                    const float* __restrict__ Wih0, const float* __restrict__ Whh0,
                    const float* __restrict__ bih0, const float* __restrict__ bhh0,
                    const float* __restrict__ Wih1, const float* __restrict__ Whh1,
                    const float* __restrict__ bih1, const float* __restrict__ bhh1,
                    const float* __restrict__ Wfc,  const float* __restrict__ bfc,
                    float* __restrict__ out, char* __restrict__ ws)
{
  const int tid  = threadIdx.x;
  const int lane = tid & 63;
  const int wave = tid >> 6;
  const int mi   = wave >> 1;   // M half (16 chains each)
  const int ni   = wave & 1;    // N half: ni=0 -> {i,g}, ni=1 -> {f,o}
  const int q    = lane >> 4;   // quad
  const int u    = lane & 15;   // unit-in-slice / frag col / frag m

  // Opaque zero: an SGPR the compiler cannot constant-fold.
  int zz;
  asm volatile("s_mov_b32 %0, 0" : "=s"(zz));

  // ---- derive (group g, member w) from the physical XCD id ----
  // 512 blocks => 64 slots/XCD => 4 groups/XCD. Slots i and i+32 land on the
  // same CU (round-robin) and differ in group => antiphase pairing.
  __shared__ int s_gw[2];
  if (tid == 0) {
    uint32_t xcc;
    asm volatile("s_getreg_b32 %0, hwreg(HW_REG_XCC_ID)" : "=s"(xcc));
    xcc &= 7;
    const int slot = atomicAdd((int*)(ws + WS_SLOT_OFF) + (size_t)xcc * 32, 1);  // device-scope, once
    s_gw[0] = (int)xcc * 4 + (slot >> 4);   // group 0..31 (4 per XCD)
    s_gw[1] = slot & 15;                    // member 0..15 (unit slice)
  }
  __syncthreads();
  const int g = s_gw[0];
  const int w = s_gw[1];

  int* ctr = (int*)(ws + (size_t)g * 128);
  _Float16* h0b = (_Float16*)(ws + WS_HBUF_OFF + (size_t)g * GROUP_WS_BYTES);
  _Float16* h1b = h0b + HBUF_ELEMS;

  __shared__ __align__(16) _Float16 sb0[HBUF_ELEMS];  // staged h0 (16KB)
  __shared__ __align__(16) _Float16 xbuf[32 * 72];    // 72-elem stride (bank pad)
  __shared__ __align__(16) float    exch[8 * 64];
  __shared__ __align__(16) float    predbuf[32 * 68];

  // ---------------- weight fragments (register-resident, f16) ----------------
  // gates = act @ W^T : A[m=chain][k], B[k][n=gate-row].  B-frag: n=lane&15, k=q*8+j.
  half8 bL0[2][10]; half8 bL1[2][16]; half8 bFC[2][8];
  float biasL0[2], biasL1[2], biasFC[2];
  #pragma unroll
  for (int nt = 0; nt < 2; ++nt) {
    // gate-type base: ni=0 tiles {i(0), g(512)}, ni=1 tiles {f(256), o(768)}
    const int base0 = (ni == 0) ? (nt == 0 ? 0 : 512) : (nt == 0 ? 256 : 768);
    const int row = base0 + w * 16 + u;
    biasL0[nt] = bih0[row] + bhh0[row];
    biasL1[nt] = bih1[row] + bhh1[row];
    #pragma unroll
    for (int kt = 0; kt < 10; ++kt) {   // L0: K = 64(x) + 256(h0)
      const int k0 = kt * 32 + q * 8;
      const float* src = (kt < 2) ? (Wih0 + (size_t)row * 64 + k0)
                                  : (Whh0 + (size_t)row * 256 + (k0 - 64));
      half8 v;
      #pragma unroll
      for (int j = 0; j < 8; ++j) v[j] = (_Float16)src[j];
      bL0[nt][kt] = v;
    }
    #pragma unroll
    for (int kt = 0; kt < 16; ++kt) {   // L1: K = 256(h0new) + 256(h1)
      const int k0 = kt * 32 + q * 8;
      const float* src = (kt < 8) ? (Wih1 + (size_t)row * 256 + k0)
                                  : (Whh1 + (size_t)row * 256 + (k0 - 256));
      half8 v;
      #pragma unroll
      for (int j = 0; j < 8; ++j) v[j] = (_Float16)src[j];
      bL1[nt][kt] = v;
    }
    const int rowF = ni * 32 + nt * 16 + u;  // FC: no reorder
    biasFC[nt] = bfc[rowF];
    #pragma unroll
    for (int kt = 0; kt < 8; ++kt) {
      const float* src = Wfc + (size_t)rowF * 256 + kt * 32 + q * 8;
      half8 v;
      #pragma unroll
      for (int j = 0; j < 8; ++j) v[j] = (_Float16)src[j];
      bFC[nt][kt] = v;
    }
  }

  // ---------------- state init ----------------
  float c0st[4], c1st[4], h0sv[4], h1sv[4];
  #pragma unroll
  for (int r = 0; r < 4; ++r) { c0st[r] = 0; c1st[r] = 0; h0sv[r] = 0; h1sv[r] = 0; }
  if (ni == 1) {  // ni=1 waves own c-state in D-frag layout
    #pragma unroll
    for (int r = 0; r < 4; ++r) {
      const int ch = g * 32 + mi * 16 + q * 4 + r;
      c0st[r] = c0in[(size_t)ch * 256 + w * 16 + u];
      c1st[r] = c0in[262144 + (size_t)ch * 256 + w * 16 + u];
    }
  }
  // initial h -> chunked L2 buffers, plain 8B stores
  for (int idx = tid; idx < 2048; idx += NTHR) {   // idx = one 4-half quarter-chunk
    const int e0 = (idx & 1) * 4;
    const int m  = (idx >> 1) & 31;
    const int c  = idx >> 6;              // chunk 0..31
    const int col = c * 8 + e0;           // global hidden-unit column
    #pragma unroll
    for (int l = 0; l < 2; ++l) {
      const float* s = h0in + (size_t)l * 262144 + (size_t)(g * 32 + m) * 256 + col;
      union { _Float16 h[4]; uint64_t u64; } pk;
      #pragma unroll
      for (int j = 0; j < 4; ++j) pk.h[j] = (_Float16)s[j];
      ((uint64_t*)(l ? h1b : h0b))[idx] = pk.u64;
    }
  }
  for (int i = tid; i < 32 * 64; i += NTHR) {  // x0 = zeros, col 61 (= INPUT_SIZE-3) = 1
    const int row = i >> 6, col = i & 63;
    xbuf[row * 72 + col] = (col == 61) ? (_Float16)1.0f : (_Float16)0.0f;
  }

  int phase = 0;
  group_barrier(ctr, &phase, zz);

  // Prologue staging: SB0 <- initial h0; hf <- initial h1 fragments (retained).
  half8 hf[8];   // loop-carried: written in FC(t), read in L1(t+1) kt8..15
  stage16k(h0b, sb0, tid);
  #pragma unroll
  for (int kt = 0; kt < 8; ++kt)
    hf[kt] = ld_frag(h1b, (kt * 4 + q) * 32 + (mi * 16 + u));
  __syncthreads();   // drains vmcnt: staging + hf loads complete, all waves

  // ---------------- time loop ----------------
  for (int t = 0; t < TSTEPS; ++t) {
    // ======== Layer 0: gates = [x | h0_prev] @ W^T  (xbuf + SB0, all LDS) ========
    {
      f32x4 acc[2];
      #pragma unroll
      for (int nt = 0; nt < 2; ++nt) {
        f32x4 v; v[0] = biasL0[nt]; v[1] = biasL0[nt]; v[2] = biasL0[nt]; v[3] = biasL0[nt];
        acc[nt] = v;
      }
      #pragma unroll
      for (int kt = 0; kt < 10; ++kt) {
        const int m = mi * 16 + u;          // A-frag: m = lane&15 within M-half
        half8 a;
        if (kt < 2) a = *(const half8*)(xbuf + m * 72 + kt * 32 + q * 8);
        else        a = *(const half8*)(sb0 + (size_t)((kt * 4 - 8 + q) * 32 + m) * 8);
        #pragma unroll
        for (int nt = 0; nt < 2; ++nt)
          acc[nt] = __builtin_amdgcn_mfma_f32_16x16x32_f16(a, bL0[nt][kt], acc[nt], 0, 0, 0);
      }
      if (ni == 0) {  // u0 = sigmoid(i)*tanh(g), in-lane (tile0=i, tile1=g)
        #pragma unroll
        for (int r = 0; r < 4; ++r)
          exch[(mi * 4 + r) * 64 + lane] = sigm(acc[0][r]) * tanh_f(acc[1][r]);
      }
      __syncthreads();
      if (ni == 1) {  // tile0=f, tile1=o
        float hv[4];
        #pragma unroll
        for (int r = 0; r < 4; ++r) {
          const float u0 = exch[(mi * 4 + r) * 64 + lane];
          const float cn = sigm(acc[0][r]) * c0st[r] + u0;
          c0st[r] = cn;
          const float hh = sigm(acc[1][r]) * tanh_f(cn);
          h0sv[r] = hh;
          hv[r] = hh;
        }
        #pragma unroll
        for (int r = 0; r < 4; ++r) {
          const float other = __shfl_xor(hv[r], 1);
          if (!(u & 1))
            store_h_pair(h0b, w, u, mi * 16 + q * 4 + r, hv[r], other);
        }
      }
    }
    group_barrier(ctr, &phase, zz);

    // restage SB0 <- h0_new (transfer overlaps the register-half MFMAs below)
    stage16k(h0b, sb0, tid);

    // ======== Layer 1: gates = [h0_new | h1_prev] @ W^T ========
    {
      f32x4 acc[2];
      #pragma unroll
      for (int nt = 0; nt < 2; ++nt) {
        f32x4 v; v[0] = biasL1[nt]; v[1] = biasL1[nt]; v[2] = biasL1[nt]; v[3] = biasL1[nt];
        acc[nt] = v;
      }
      // h1_prev half (kt 8..15): A-frags retained in registers from FC(t-1).
      // Pure-register MFMAs — run while SB0 staging is in flight.
      #pragma unroll
      for (int kk = 0; kk < 8; ++kk)
        #pragma unroll
        for (int nt = 0; nt < 2; ++nt)
          acc[nt] = __builtin_amdgcn_mfma_f32_16x16x32_f16(hf[kk], bL1[nt][kk + 8], acc[nt], 0, 0, 0);
      __syncthreads();   // vmcnt(0) drain: all waves' SB0 staging complete
      // h0_new half (kt 0..7) from SB0 (LDS)
      #pragma unroll
      for (int kt = 0; kt < 8; ++kt) {
        const int m = mi * 16 + u;
        const half8 a = *(const half8*)(sb0 + (size_t)((kt * 4 + q) * 32 + m) * 8);
        #pragma unroll
        for (int nt = 0; nt < 2; ++nt)
          acc[nt] = __builtin_amdgcn_mfma_f32_16x16x32_f16(a, bL1[nt][kt], acc[nt], 0, 0, 0);
      }
      if (ni == 0) {
        #pragma unroll
        for (int r = 0; r < 4; ++r)
          exch[(mi * 4 + r) * 64 + lane] = sigm(acc[0][r]) * tanh_f(acc[1][r]);
      }
      __syncthreads();
      if (ni == 1) {
        float hv[4];
        #pragma unroll
        for (int r = 0; r < 4; ++r) {
          const float u0 = exch[(mi * 4 + r) * 64 + lane];
          const float cn = sigm(acc[0][r]) * c1st[r] + u0;
          c1st[r] = cn;
          const float hh = sigm(acc[1][r]) * tanh_f(cn);
          h1sv[r] = hh;
          hv[r] = hh;
        }
        #pragma unroll
        for (int r = 0; r < 4; ++r) {
          const float other = __shfl_xor(hv[r], 1);
          if (!(u & 1))
            store_h_pair(h1b, w, u, mi * 16 + q * 4 + r, hv[r], other);
        }
      }
    }
    group_barrier(ctr, &phase, zz);

    // ======== FC + log_softmax (computed redundantly per WG) ========
    {
      // Batched direct loads of h1_new fragments; RETAINED into L1(t+1).
      #pragma unroll
      for (int kt = 0; kt < 8; ++kt)
        hf[kt] = ld_frag(h1b, (kt * 4 + q) * 32 + (mi * 16 + u));
      f32x4 acc[2];
      #pragma unroll
      for (int nt = 0; nt < 2; ++nt) {
        f32x4 v; v[0] = biasFC[nt]; v[1] = biasFC[nt]; v[2] = biasFC[nt]; v[3] = biasFC[nt];
        acc[nt] = v;
      }
      #pragma unroll
      for (int kt = 0; kt < 8; ++kt)
        #pragma unroll
        for (int nt = 0; nt < 2; ++nt)
          acc[nt] = __builtin_amdgcn_mfma_f32_16x16x32_f16(hf[kt], bFC[nt][kt], acc[nt], 0, 0, 0);
      #pragma unroll
      for (int nt = 0; nt < 2; ++nt)
        #pragma unroll
        for (int r = 0; r < 4; ++r)
          predbuf[(mi * 16 + q * 4 + r) * 68 + ni * 32 + nt * 16 + u] = acc[nt][r];
    }
    __syncthreads();
    {
      const int row = tid >> 3;   // group-local chain (0..31)
      const int cg  = tid & 7;    // 8-col group
      const float* pr = predbuf + row * 68 + cg * 8;
      float p[8];
      #pragma unroll
      for (int j = 0; j < 8; ++j) p[j] = pr[j];
      float mx = -3.0e38f;
      #pragma unroll
      for (int j = 0; j < 8; ++j)
        if (!(cg == 7 && j == 7)) mx = fmaxf(mx, p[j]);   // exclude col 63 (dur)
      mx = fmaxf(mx, __shfl_xor(mx, 1));
      mx = fmaxf(mx, __shfl_xor(mx, 2));
      mx = fmaxf(mx, __shfl_xor(mx, 4));
      float sm = 0.0f;
      #pragma unroll
      for (int j = 0; j < 8; ++j)
        if (!(cg == 7 && j == 7)) sm += __expf(p[j] - mx);
      sm += __shfl_xor(sm, 1);
      sm += __shfl_xor(sm, 2);
      sm += __shfl_xor(sm, 4);
      const float lz = mx + __logf(sm);
      float o[8];
      #pragma unroll
      for (int j = 0; j < 8; ++j) o[j] = p[j] - lz;
      if (cg == 7) o[7] = sigm(p[7]);                      // duration = sigmoid(pred[63])
      _Float16* xw = xbuf + row * 72 + cg * 8;             // feedback x = out (f16)
      #pragma unroll
      for (int j = 0; j < 8; ++j) xw[j] = (_Float16)o[j];
      if ((row >> 1) == w) {                               // each WG writes 2 of the 32 rows
        const int ch = g * 32 + row;
        float* dst = out + ((size_t)ch * TSTEPS + t) * 64 + cg * 8;
        #pragma unroll
        for (int j = 0; j < 8; ++j) dst[j] = o[j];
      }
    }
    __syncthreads();
  }

  // ---------------- final h_f, c_f ----------------
  if (ni == 1) {
    float* hfp = out + OUT_ELEMS;
    float* cfp = out + OUT_ELEMS + HF_ELEMS;
    #pragma unroll
    for (int r = 0; r < 4; ++r) {
      const int ch = g * 32 + mi * 16 + q * 4 + r;
      const size_t idx = (size_t)ch * 256 + w * 16 + u;
      hfp[idx] = h0sv[r];
      hfp[262144 + idx] = h1sv[r];
      cfp[idx] = c0st[r];
      cfp[262144 + idx] = c1st[r];
    }
  }
}

extern "C" void kernel_launch(void* const* d_in, const int* in_sizes, int n_in,
                              void* d_out, int out_size, void* d_ws, size_t ws_size,
                              hipStream_t stream) {
  (void)in_sizes; (void)n_in; (void)out_size;
  if (ws_size < (size_t)WS_NEEDED) return;

  const float* h0   = (const float*)d_in[1];
  const float* c0   = (const float*)d_in[2];
  const float* Wih0 = (const float*)d_in[3];
  const float* Whh0 = (const float*)d_in[4];
  const float* bih0 = (const float*)d_in[5];
  const float* bhh0 = (const float*)d_in[6];
  const float* Wih1 = (const float*)d_in[7];
  const float* Whh1 = (const float*)d_in[8];
  const float* bih1 = (const float*)d_in[9];
  const float* bhh1 = (const float*)d_in[10];
  const float* Wfc  = (const float*)d_in[11];
  const float* bfc  = (const float*)d_in[12];
  float* outp = (float*)d_out;
  char*  wsp  = (char*)d_ws;

  // zero barrier + slot counters (ws is re-poisoned to 0xAA before every
  // launch; end-of-dispatch flush of the memset makes zeros globally visible)
  hipMemsetAsync(d_ws, 0, WS_HBUF_OFF, stream);

  void* args[] = { &h0, &c0, &Wih0, &Whh0, &bih0, &bhh0, &Wih1, &Whh1,
                   &bih1, &bhh1, &Wfc, &bfc, &outp, &wsp };
  hipError_t e = hipLaunchCooperativeKernel((const void*)decoder_kernel,
                                            dim3(NGROUP * GWG), dim3(NTHR),
                                            args, 0u, stream);
  if (e != hipSuccess) {
    // fallback: plain launch (512 blocks at 2/CU are co-resident)
    decoder_kernel<<<dim3(NGROUP * GWG), dim3(NTHR), 0, stream>>>(
        h0, c0, Wih0, Whh0, bih0, bhh0, Wih1, Whh1, bih1, bhh1, Wfc, bfc, outp, wsp);
  }
}

// Round 3
// 5180.305 us; speedup vs baseline: 1.9738x; 1.9738x over previous
//
#include <hip/hip_runtime.h>
#include <stdint.h>
#include <stddef.h>

// Persistent 2-layer LSTM decoder, B=1024, H=256, T=512.
// 16 groups x 16 WGs x 256 threads (1 block/CU). WG owns 16 hidden units,
// weights register-resident as f16 MFMA B-fragments (parked in AGPRs by the
// compiler at occupancy 1: 512 unified VGPR+AGPR budget).
//
// R7: split-phase barriers + latency-window filling. R5 was latency-bound
// (~16k of 22.9k cyc/step idle at occupancy 1); R6 (2 waves/SIMD) proved
// register-resident weights cannot fit 128 VGPR (20.6GB scratch spill).
// So the PROGRAM fills its own stall windows:
//  - b2 arrive->wait window: L0(t+1) h-part kt2..5 (needs only SB0=h0(t)).
//  - post-b2 hf-load window: L0(t+1) h-part kt6..9 runs while the 16 hf
//    fragment loads (h1(t) from L2) are in flight.
//  - b1 arrive->wait window: L1(t+1) reg-half kk0..3 (needs only hf regs).
//  - SB0 stage-drain window: L1(t+1) reg-half kk4..7.
// barrier_arrive = fire-and-forget no-return atomic add (after the drain
// syncthreads); barrier_wait = RMW poll + buffer_inv sc0 + syncthreads.
// All overlap work touches only registers/LDS/own SB0 => race-free: every
// h-buffer write is separated from its cross-WG read by a full arrive/wait.
//
// Data path otherwise = R5: SB0 (32KB LDS) staged via global_load_lds after
// b1; h1 A-frags retained in registers across b2 (FC(t) frags == L1(t+1)
// h1_prev frags); single L2 h-buffer per group/layer; XCD-local groups
// (HW_REG_XCC_ID + slot claim); write-through stores + buffer_inv acquire.
//
// h-buffer layout (per group, per layer): chunked f16
//   f16_index = (c*64 + m)*8 + e,  c = k/8 (0..31), m = chain row (0..63),
//   e = k%8; an MFMA A-fragment is one 16B chunk; chunk c is a contiguous
//   1KB block (=> linear global_load_lds copy).

#define NGROUP 16
#define GWG    16
#define NTHR   256
#define TSTEPS 512

typedef _Float16 half8 __attribute__((ext_vector_type(8)));
typedef float    f32x4 __attribute__((ext_vector_type(4)));

#define OUT_ELEMS   33554432   // 1024*512*64
#define HF_ELEMS    524288     // 2*1024*256
#define HBUF_ELEMS  16384      // 64*256 (f16) per layer
#define GROUP_WS_BYTES 65536   // 2 layers * 32KB
#define WS_HBUF_OFF 4096
#define WS_NEEDED   (WS_HBUF_OFF + NGROUP * GROUP_WS_BYTES)

__device__ __forceinline__ float sigm(float x)   { return 1.0f / (1.0f + __expf(-x)); }
__device__ __forceinline__ float tanh_f(float x) { return 1.0f - 2.0f / (__expf(2.0f * x) + 1.0f); }

// Split-phase XCD-local group barrier. Caller must __syncthreads() (vmcnt
// drain = release to XCD L2, write-through L1) BEFORE barrier_arrive.
// Arrive is a no-return global_atomic_add (fire-and-forget). Wait polls with
// a real RMW (zz = opaque zero defeats the atomicrmw-add-0 -> load fold),
// then invalidates L1 only (acquire) and rendezvous the block.
__device__ __forceinline__ void barrier_arrive(int* ctr) {
  if (threadIdx.x == 0)
    __hip_atomic_fetch_add(ctr, 1, __ATOMIC_RELEASE, __HIP_MEMORY_SCOPE_WORKGROUP);
}
__device__ __forceinline__ void barrier_wait(int* ctr, int* phase, int zz) {
  if (threadIdx.x == 0) {
    const int target = GWG * (++(*phase));
    while (__hip_atomic_fetch_add(ctr, zz, __ATOMIC_RELAXED, __HIP_MEMORY_SCOPE_WORKGROUP) < target)
      __builtin_amdgcn_s_sleep(1);
    asm volatile("buffer_inv sc0" ::: "memory");   // L1-only invalidate (gfx940+)
  }
  __syncthreads();
}

// 16B A-fragment plain load from a chunked h-buffer in L2.
__device__ __forceinline__ half8 ld_frag(const _Float16* buf, int idx16) {
  return *(const half8*)(buf + (size_t)idx16 * 8);
}

// 32KB linear global->LDS copy, zero VGPR destination. 8 insts/wave, wave wv
// handles 1KB blocks {i*4+wv}. LDS dest = wave-uniform base + lane*16.
__device__ __forceinline__ void stage32k(const void* src, void* lds_dst, int tid) {
  const int wv = tid >> 6;
  const int ln = tid & 63;
  const char* s = (const char*)src + ln * 16;
  char* d = (char*)lds_dst;
  #pragma unroll
  for (int i = 0; i < 8; ++i) {
    const int off = (i * 4 + wv) * 1024;
    __builtin_amdgcn_global_load_lds(
        (const __attribute__((address_space(1))) void*)(s + off),
        (__attribute__((address_space(3))) void*)(d + off),
        16, 0, 0);
  }
}

// Packed f16x2 plain store of (col u, col u+1) for row mh. Even-u lanes only.
__device__ __forceinline__ void store_h_pair(_Float16* hw, int w, int u, int mh,
                                             float lo, float hi) {
  union { _Float16 h[2]; uint32_t u32; } pk;
  pk.h[0] = (_Float16)lo; pk.h[1] = (_Float16)hi;
  const int c = w * 2 + (u >> 3);
  *((uint32_t*)hw + (size_t)(c * 64 + mh) * 4 + ((u & 7) >> 1)) = pk.u32;
}

__global__ __launch_bounds__(NTHR, 1)
void decoder_kernel(const float* __restrict__ h0in, const float* __restrict__ c0in,
                    const float* __restrict__ Wih0, const float* __restrict__ Whh0,
                    const float* __restrict__ bih0, const float* __restrict__ bhh0,
                    const float* __restrict__ Wih1, const float* __restrict__ Whh1,
                    const float* __restrict__ bih1, const float* __restrict__ bhh1,
                    const float* __restrict__ Wfc,  const float* __restrict__ bfc,
                    float* __restrict__ out, char* __restrict__ ws)
{
  const int tid  = threadIdx.x;
  const int lane = tid & 63;
  const int wave = tid >> 6;
  const int mi   = wave >> 1;   // M half (32 chains)
  const int ni   = wave & 1;    // N half: ni=0 -> {i,g}, ni=1 -> {f,o}
  const int q    = lane >> 4;   // quad
  const int u    = lane & 15;   // unit-in-slice / frag col / frag m

  // Opaque zero: an SGPR the compiler cannot constant-fold.
  int zz;
  asm volatile("s_mov_b32 %0, 0" : "=s"(zz));

  // ---- derive (group g, member w) from the physical XCD id ----
  __shared__ int s_gw[2];
  if (tid == 0) {
    uint32_t xcc;
    asm volatile("s_getreg_b32 %0, hwreg(HW_REG_XCC_ID)" : "=s"(xcc));
    xcc &= 7;
    const int slot = atomicAdd((int*)(ws + 2048) + (size_t)xcc * 32, 1);  // device-scope, once
    s_gw[0] = (int)xcc * 2 + (slot >> 4);   // group 0..15 (2 per XCD)
    s_gw[1] = slot & 15;                    // member 0..15 (unit slice)
  }
  __syncthreads();
  const int g = s_gw[0];
  const int w = s_gw[1];

  int* ctr = (int*)(ws + (size_t)g * 128);
  _Float16* h0b = (_Float16*)(ws + WS_HBUF_OFF + (size_t)g * GROUP_WS_BYTES);
  _Float16* h1b = h0b + HBUF_ELEMS;

  __shared__ __align__(16) _Float16 sb0[HBUF_ELEMS];  // staged h0 (32KB)
  __shared__ __align__(16) _Float16 xbuf[64 * 72];    // 72-elem stride (bank pad)
  __shared__ __align__(16) float    exch[2 * 8 * 64];
  __shared__ __align__(16) float    predbuf[64 * 68];

  // ---------------- weight fragments (register-resident, f16) ----------------
  // gates = act @ W^T : A[m=chain][k], B[k][n=gate-row].  B-frag: n=lane&15, k=q*8+j.
  half8 bL0[2][10]; half8 bL1[2][16]; half8 bFC[2][8];
  float biasL0[2], biasL1[2], biasFC[2];
  #pragma unroll
  for (int nt = 0; nt < 2; ++nt) {
    // gate-type base: ni=0 tiles {i(0), g(512)}, ni=1 tiles {f(256), o(768)}
    const int base0 = (ni == 0) ? (nt == 0 ? 0 : 512) : (nt == 0 ? 256 : 768);
    const int row = base0 + w * 16 + u;
    biasL0[nt] = bih0[row] + bhh0[row];
    biasL1[nt] = bih1[row] + bhh1[row];
    #pragma unroll
    for (int kt = 0; kt < 10; ++kt) {   // L0: K = 64(x) + 256(h0)
      const int k0 = kt * 32 + q * 8;
      const float* src = (kt < 2) ? (Wih0 + (size_t)row * 64 + k0)
                                  : (Whh0 + (size_t)row * 256 + (k0 - 64));
      half8 v;
      #pragma unroll
      for (int j = 0; j < 8; ++j) v[j] = (_Float16)src[j];
      bL0[nt][kt] = v;
    }
    #pragma unroll
    for (int kt = 0; kt < 16; ++kt) {   // L1: K = 256(h0new) + 256(h1)
      const int k0 = kt * 32 + q * 8;
      const float* src = (kt < 8) ? (Wih1 + (size_t)row * 256 + k0)
                                  : (Whh1 + (size_t)row * 256 + (k0 - 256));
      half8 v;
      #pragma unroll
      for (int j = 0; j < 8; ++j) v[j] = (_Float16)src[j];
      bL1[nt][kt] = v;
    }
    const int rowF = ni * 32 + nt * 16 + u;  // FC: no reorder
    biasFC[nt] = bfc[rowF];
    #pragma unroll
    for (int kt = 0; kt < 8; ++kt) {
      const float* src = Wfc + (size_t)rowF * 256 + kt * 32 + q * 8;
      half8 v;
      #pragma unroll
      for (int j = 0; j < 8; ++j) v[j] = (_Float16)src[j];
      bFC[nt][kt] = v;
    }
  }

  // ---------------- state init ----------------
  float c0st[2][4], c1st[2][4], h0sv[2][4], h1sv[2][4];
  #pragma unroll
  for (int mt = 0; mt < 2; ++mt)
    #pragma unroll
    for (int r = 0; r < 4; ++r) { c0st[mt][r] = 0; c1st[mt][r] = 0; h0sv[mt][r] = 0; h1sv[mt][r] = 0; }
  if (ni == 1) {  // ni=1 waves own c-state in D-frag layout
    #pragma unroll
    for (int mt = 0; mt < 2; ++mt)
      #pragma unroll
      for (int r = 0; r < 4; ++r) {
        const int ch = g * 64 + mi * 32 + mt * 16 + q * 4 + r;
        c0st[mt][r] = c0in[(size_t)ch * 256 + w * 16 + u];
        c1st[mt][r] = c0in[262144 + (size_t)ch * 256 + w * 16 + u];
      }
  }
  {  // initial h -> chunked L2 buffers, plain 8B stores (own 16-unit slice)
    const int gi = tid * 4;             // 4 consecutive f16 per thread
    const int e0 = gi & 7;              // 0 or 4
    const int m  = (gi >> 3) & 63;
    const int cc = gi >> 9;             // 0 or 1
    const int c  = w * 2 + cc;
    const int col = c * 8 + e0;         // global hidden-unit column
    #pragma unroll
    for (int l = 0; l < 2; ++l) {
      const float* s = h0in + (size_t)l * 262144 + (size_t)(g * 64 + m) * 256 + col;
      union { _Float16 h[4]; uint64_t u64; } pk;
      #pragma unroll
      for (int j = 0; j < 4; ++j) pk.h[j] = (_Float16)s[j];
      *((uint64_t*)(l ? h1b : h0b) + ((size_t)(c * 64 + m) * 2 + (e0 >> 2))) = pk.u64;
    }
  }
  for (int i = tid; i < 64 * 64; i += NTHR) {  // x0 = zeros, col 61 (= INPUT_SIZE-3) = 1
    const int row = i >> 6, col = i & 63;
    xbuf[row * 72 + col] = (col == 61) ? (_Float16)1.0f : (_Float16)0.0f;
  }

  int phase = 0;
  __syncthreads();
  barrier_arrive(ctr);
  barrier_wait(ctr, &phase, zz);

  // Prologue staging: SB0 <- h0(-1); hf <- h1(-1) fragments (retained).
  half8 hf[8][2];   // loop-carried: loaded in FC(t), consumed by L1(t+1) kt8..15
  stage32k(h0b, sb0, tid);
  #pragma unroll
  for (int kt = 0; kt < 8; ++kt)
    #pragma unroll
    for (int mt = 0; mt < 2; ++mt)
      hf[kt][mt] = ld_frag(h1b, (kt * 4 + q) * 64 + (mi * 32 + mt * 16 + u));
  __syncthreads();   // drains vmcnt: staging + hf loads complete, all waves

  // ---------------- prologue: L0(0) ----------------
  {
    f32x4 acc[2][2];
    #pragma unroll
    for (int mt = 0; mt < 2; ++mt)
      #pragma unroll
      for (int nt = 0; nt < 2; ++nt) {
        f32x4 v; v[0] = biasL0[nt]; v[1] = biasL0[nt]; v[2] = biasL0[nt]; v[3] = biasL0[nt];
        acc[mt][nt] = v;
      }
    #pragma unroll
    for (int kt = 0; kt < 10; ++kt) {
      half8 a[2];
      #pragma unroll
      for (int mt = 0; mt < 2; ++mt) {
        const int m = mi * 32 + mt * 16 + u;
        if (kt < 2) a[mt] = *(const half8*)(xbuf + m * 72 + kt * 32 + q * 8);
        else        a[mt] = *(const half8*)(sb0 + (size_t)((kt * 4 - 8 + q) * 64 + m) * 8);
      }
      #pragma unroll
      for (int mt = 0; mt < 2; ++mt)
        #pragma unroll
        for (int nt = 0; nt < 2; ++nt)
          acc[mt][nt] = __builtin_amdgcn_mfma_f32_16x16x32_f16(a[mt], bL0[nt][kt], acc[mt][nt], 0, 0, 0);
    }
    if (ni == 0) {
      #pragma unroll
      for (int mt = 0; mt < 2; ++mt)
        #pragma unroll
        for (int r = 0; r < 4; ++r)
          exch[(mi * 8 + mt * 4 + r) * 64 + lane] = sigm(acc[mt][0][r]) * tanh_f(acc[mt][1][r]);
    }
    __syncthreads();
    if (ni == 1) {
      float hv[2][4];
      #pragma unroll
      for (int mt = 0; mt < 2; ++mt)
        #pragma unroll
        for (int r = 0; r < 4; ++r) {
          const float u0 = exch[(mi * 8 + mt * 4 + r) * 64 + lane];
          const float cn = sigm(acc[mt][0][r]) * c0st[mt][r] + u0;
          c0st[mt][r] = cn;
          const float hh = sigm(acc[mt][1][r]) * tanh_f(cn);
          h0sv[mt][r] = hh;
          hv[mt][r] = hh;
        }
      #pragma unroll
      for (int mt = 0; mt < 2; ++mt)
        #pragma unroll
        for (int r = 0; r < 4; ++r) {
          const float other = __shfl_xor(hv[mt][r], 1);
          if (!(u & 1))
            store_h_pair(h0b, w, u, mi * 32 + mt * 16 + q * 4 + r, hv[mt][r], other);
        }
    }
  }
  __syncthreads();            // drain h0(0) stores
  barrier_arrive(ctr);        // b1(0)

  // L1(0) reg-half kk0..3 covers b1; kk4..7 covers the SB0 restage.
  f32x4 acc1[2][2];           // loop-carried L1 accumulator
  #pragma unroll
  for (int mt = 0; mt < 2; ++mt)
    #pragma unroll
    for (int nt = 0; nt < 2; ++nt) {
      f32x4 v; v[0] = biasL1[nt]; v[1] = biasL1[nt]; v[2] = biasL1[nt]; v[3] = biasL1[nt];
      acc1[mt][nt] = v;
    }
  #pragma unroll
  for (int kk = 0; kk < 4; ++kk)
    #pragma unroll
    for (int mt = 0; mt < 2; ++mt)
      #pragma unroll
      for (int nt = 0; nt < 2; ++nt)
        acc1[mt][nt] = __builtin_amdgcn_mfma_f32_16x16x32_f16(hf[kk][mt], bL1[nt][kk + 8], acc1[mt][nt], 0, 0, 0);
  barrier_wait(ctr, &phase, zz);
  stage32k(h0b, sb0, tid);    // SB0 <- h0(0)
  #pragma unroll
  for (int kk = 4; kk < 8; ++kk)
    #pragma unroll
    for (int mt = 0; mt < 2; ++mt)
      #pragma unroll
      for (int nt = 0; nt < 2; ++nt)
        acc1[mt][nt] = __builtin_amdgcn_mfma_f32_16x16x32_f16(hf[kk][mt], bL1[nt][kk + 8], acc1[mt][nt], 0, 0, 0);

  // ---------------- time loop: iter t computes L1(t), FC(t), L0(t+1) ----------------
  for (int t = 0; t < TSTEPS; ++t) {
    __syncthreads();   // drains SB0 stage (h0(t)) for all waves
    // ======== L1(t) LDS-half: kt0..7 from SB0 ========
    #pragma unroll
    for (int kt = 0; kt < 8; ++kt) {
      half8 a[2];
      #pragma unroll
      for (int mt = 0; mt < 2; ++mt) {
        const int m = mi * 32 + mt * 16 + u;
        a[mt] = *(const half8*)(sb0 + (size_t)((kt * 4 + q) * 64 + m) * 8);
      }
      #pragma unroll
      for (int mt = 0; mt < 2; ++mt)
        #pragma unroll
        for (int nt = 0; nt < 2; ++nt)
          acc1[mt][nt] = __builtin_amdgcn_mfma_f32_16x16x32_f16(a[mt], bL1[nt][kt], acc1[mt][nt], 0, 0, 0);
    }
    // ======== L1(t) gates ========
    if (ni == 0) {
      #pragma unroll
      for (int mt = 0; mt < 2; ++mt)
        #pragma unroll
        for (int r = 0; r < 4; ++r)
          exch[(mi * 8 + mt * 4 + r) * 64 + lane] = sigm(acc1[mt][0][r]) * tanh_f(acc1[mt][1][r]);
    }
    __syncthreads();
    if (ni == 1) {
      float hv[2][4];
      #pragma unroll
      for (int mt = 0; mt < 2; ++mt)
        #pragma unroll
        for (int r = 0; r < 4; ++r) {
          const float u0 = exch[(mi * 8 + mt * 4 + r) * 64 + lane];
          const float cn = sigm(acc1[mt][0][r]) * c1st[mt][r] + u0;
          c1st[mt][r] = cn;
          const float hh = sigm(acc1[mt][1][r]) * tanh_f(cn);
          h1sv[mt][r] = hh;
          hv[mt][r] = hh;
        }
      #pragma unroll
      for (int mt = 0; mt < 2; ++mt)
        #pragma unroll
        for (int r = 0; r < 4; ++r) {
          const float other = __shfl_xor(hv[mt][r], 1);
          if (!(u & 1))
            store_h_pair(h1b, w, u, mi * 32 + mt * 16 + q * 4 + r, hv[mt][r], other);
        }
    }
    __syncthreads();           // drain h1(t) stores
    barrier_arrive(ctr);       // b2(t)

    // ---- b2 window: L0(t+1) h-part kt2..5 (SB0 = h0(t) still current) ----
    f32x4 acc0[2][2];
    #pragma unroll
    for (int mt = 0; mt < 2; ++mt)
      #pragma unroll
      for (int nt = 0; nt < 2; ++nt) {
        f32x4 v; v[0] = biasL0[nt]; v[1] = biasL0[nt]; v[2] = biasL0[nt]; v[3] = biasL0[nt];
        acc0[mt][nt] = v;
      }
    #pragma unroll
    for (int kt = 2; kt < 6; ++kt) {
      half8 a[2];
      #pragma unroll
      for (int mt = 0; mt < 2; ++mt) {
        const int m = mi * 32 + mt * 16 + u;
        a[mt] = *(const half8*)(sb0 + (size_t)((kt * 4 - 8 + q) * 64 + m) * 8);
      }
      #pragma unroll
      for (int mt = 0; mt < 2; ++mt)
        #pragma unroll
        for (int nt = 0; nt < 2; ++nt)
          acc0[mt][nt] = __builtin_amdgcn_mfma_f32_16x16x32_f16(a[mt], bL0[nt][kt], acc0[mt][nt], 0, 0, 0);
    }
    barrier_wait(ctr, &phase, zz);   // b2 done: h1(t) visible

    // ======== FC(t): issue hf loads, cover with L0 h-part kt6..9 ========
    #pragma unroll
    for (int kt = 0; kt < 8; ++kt)
      #pragma unroll
      for (int mt = 0; mt < 2; ++mt)
        hf[kt][mt] = ld_frag(h1b, (kt * 4 + q) * 64 + (mi * 32 + mt * 16 + u));
    #pragma unroll
    for (int kt = 6; kt < 10; ++kt) {
      half8 a[2];
      #pragma unroll
      for (int mt = 0; mt < 2; ++mt) {
        const int m = mi * 32 + mt * 16 + u;
        a[mt] = *(const half8*)(sb0 + (size_t)((kt * 4 - 8 + q) * 64 + m) * 8);
      }
      #pragma unroll
      for (int mt = 0; mt < 2; ++mt)
        #pragma unroll
        for (int nt = 0; nt < 2; ++nt)
          acc0[mt][nt] = __builtin_amdgcn_mfma_f32_16x16x32_f16(a[mt], bL0[nt][kt], acc0[mt][nt], 0, 0, 0);
    }
    {
      f32x4 accF[2][2];
      #pragma unroll
      for (int mt = 0; mt < 2; ++mt)
        #pragma unroll
        for (int nt = 0; nt < 2; ++nt) {
          f32x4 v; v[0] = biasFC[nt]; v[1] = biasFC[nt]; v[2] = biasFC[nt]; v[3] = biasFC[nt];
          accF[mt][nt] = v;
        }
      #pragma unroll
      for (int kt = 0; kt < 8; ++kt)
        #pragma unroll
        for (int mt = 0; mt < 2; ++mt)
          #pragma unroll
          for (int nt = 0; nt < 2; ++nt)
            accF[mt][nt] = __builtin_amdgcn_mfma_f32_16x16x32_f16(hf[kt][mt], bFC[nt][kt], accF[mt][nt], 0, 0, 0);
      #pragma unroll
      for (int mt = 0; mt < 2; ++mt)
        #pragma unroll
        for (int nt = 0; nt < 2; ++nt)
          #pragma unroll
          for (int r = 0; r < 4; ++r)
            predbuf[(mi * 32 + mt * 16 + q * 4 + r) * 68 + ni * 32 + nt * 16 + u] = accF[mt][nt][r];
    }
    __syncthreads();
    // ======== softmax + out + feedback ========
    {
      const int row = tid >> 2;   // group-local chain
      const int cg  = tid & 3;    // 16-col group
      const float* pr = predbuf + row * 68 + cg * 16;
      float p[16];
      #pragma unroll
      for (int j = 0; j < 16; ++j) p[j] = pr[j];
      float mx = -3.0e38f;
      #pragma unroll
      for (int j = 0; j < 16; ++j)
        if (!(cg == 3 && j == 15)) mx = fmaxf(mx, p[j]);   // exclude col 63 (dur)
      mx = fmaxf(mx, __shfl_xor(mx, 1));
      mx = fmaxf(mx, __shfl_xor(mx, 2));
      float sm = 0.0f;
      #pragma unroll
      for (int j = 0; j < 16; ++j)
        if (!(cg == 3 && j == 15)) sm += __expf(p[j] - mx);
      sm += __shfl_xor(sm, 1);
      sm += __shfl_xor(sm, 2);
      const float lz = mx + __logf(sm);
      float o[16];
      #pragma unroll
      for (int j = 0; j < 16; ++j) o[j] = p[j] - lz;
      if (cg == 3) o[15] = sigm(p[15]);                    // duration = sigmoid(pred[63])
      _Float16* xw = xbuf + row * 72 + cg * 16;            // feedback x = out (f16)
      #pragma unroll
      for (int j = 0; j < 16; ++j) xw[j] = (_Float16)o[j];
      if ((row >> 2) == w) {                               // each WG writes 4 of the 64 rows
        const int ch = g * 64 + row;
        float* dst = out + ((size_t)ch * TSTEPS + t) * 64 + cg * 16;
        #pragma unroll
        for (int j = 0; j < 16; ++j) dst[j] = o[j];
      }
    }
    __syncthreads();

    if (t + 1 < TSTEPS) {
      // ======== L0(t+1) x-part + gates ========
      #pragma unroll
      for (int kt = 0; kt < 2; ++kt) {
        half8 a[2];
        #pragma unroll
        for (int mt = 0; mt < 2; ++mt) {
          const int m = mi * 32 + mt * 16 + u;
          a[mt] = *(const half8*)(xbuf + m * 72 + kt * 32 + q * 8);
        }
        #pragma unroll
        for (int mt = 0; mt < 2; ++mt)
          #pragma unroll
          for (int nt = 0; nt < 2; ++nt)
            acc0[mt][nt] = __builtin_amdgcn_mfma_f32_16x16x32_f16(a[mt], bL0[nt][kt], acc0[mt][nt], 0, 0, 0);
      }
      if (ni == 0) {
        #pragma unroll
        for (int mt = 0; mt < 2; ++mt)
          #pragma unroll
          for (int r = 0; r < 4; ++r)
            exch[(mi * 8 + mt * 4 + r) * 64 + lane] = sigm(acc0[mt][0][r]) * tanh_f(acc0[mt][1][r]);
      }
      __syncthreads();
      if (ni == 1) {
        float hv[2][4];
        #pragma unroll
        for (int mt = 0; mt < 2; ++mt)
          #pragma unroll
          for (int r = 0; r < 4; ++r) {
            const float u0 = exch[(mi * 8 + mt * 4 + r) * 64 + lane];
            const float cn = sigm(acc0[mt][0][r]) * c0st[mt][r] + u0;
            c0st[mt][r] = cn;
            const float hh = sigm(acc0[mt][1][r]) * tanh_f(cn);
            h0sv[mt][r] = hh;
            hv[mt][r] = hh;
          }
        #pragma unroll
        for (int mt = 0; mt < 2; ++mt)
          #pragma unroll
          for (int r = 0; r < 4; ++r) {
            const float other = __shfl_xor(hv[mt][r], 1);
            if (!(u & 1))
              store_h_pair(h0b, w, u, mi * 32 + mt * 16 + q * 4 + r, hv[mt][r], other);
          }
      }
      __syncthreads();           // drain h0(t+1) stores
      barrier_arrive(ctr);       // b1(t+1)
      // ---- b1 window: L1(t+1) reg-half kk0..3 (hf = h1(t)) ----
      #pragma unroll
      for (int mt = 0; mt < 2; ++mt)
        #pragma unroll
        for (int nt = 0; nt < 2; ++nt) {
          f32x4 v; v[0] = biasL1[nt]; v[1] = biasL1[nt]; v[2] = biasL1[nt]; v[3] = biasL1[nt];
          acc1[mt][nt] = v;
        }
      #pragma unroll
      for (int kk = 0; kk < 4; ++kk)
        #pragma unroll
        for (int mt = 0; mt < 2; ++mt)
          #pragma unroll
          for (int nt = 0; nt < 2; ++nt)
            acc1[mt][nt] = __builtin_amdgcn_mfma_f32_16x16x32_f16(hf[kk][mt], bL1[nt][kk + 8], acc1[mt][nt], 0, 0, 0);
      barrier_wait(ctr, &phase, zz);
      // ---- stage window: restage SB0 <- h0(t+1), cover with kk4..7 ----
      stage32k(h0b, sb0, tid);
      #pragma unroll
      for (int kk = 4; kk < 8; ++kk)
        #pragma unroll
        for (int mt = 0; mt < 2; ++mt)
          #pragma unroll
          for (int nt = 0; nt < 2; ++nt)
            acc1[mt][nt] = __builtin_amdgcn_mfma_f32_16x16x32_f16(hf[kk][mt], bL1[nt][kk + 8], acc1[mt][nt], 0, 0, 0);
    }
  }

  // ---------------- final h_f, c_f ----------------
  if (ni == 1) {
    float* hfp = out + OUT_ELEMS;
    float* cfp = out + OUT_ELEMS + HF_ELEMS;
    #pragma unroll
    for (int mt = 0; mt < 2; ++mt)
      #pragma unroll
      for (int r = 0; r < 4; ++r) {
        const int ch = g * 64 + mi * 32 + mt * 16 + q * 4 + r;
        const size_t idx = (size_t)ch * 256 + w * 16 + u;
        hfp[idx] = h0sv[mt][r];
        hfp[262144 + idx] = h1sv[mt][r];
        cfp[idx] = c0st[mt][r];
        cfp[262144 + idx] = c1st[mt][r];
      }
  }
}

extern "C" void kernel_launch(void* const* d_in, const int* in_sizes, int n_in,
                              void* d_out, int out_size, void* d_ws, size_t ws_size,
                              hipStream_t stream) {
  (void)in_sizes; (void)n_in; (void)out_size;
  if (ws_size < (size_t)WS_NEEDED) return;

  const float* h0   = (const float*)d_in[1];
  const float* c0   = (const float*)d_in[2];
  const float* Wih0 = (const float*)d_in[3];
  const float* Whh0 = (const float*)d_in[4];
  const float* bih0 = (const float*)d_in[5];
  const float* bhh0 = (const float*)d_in[6];
  const float* Wih1 = (const float*)d_in[7];
  const float* Whh1 = (const float*)d_in[8];
  const float* bih1 = (const float*)d_in[9];
  const float* bhh1 = (const float*)d_in[10];
  const float* Wfc  = (const float*)d_in[11];
  const float* bfc  = (const float*)d_in[12];
  float* outp = (float*)d_out;
  char*  wsp  = (char*)d_ws;

  // zero barrier + slot counters (ws is re-poisoned to 0xAA before every
  // launch; end-of-dispatch flush of the memset makes zeros globally visible)
  hipMemsetAsync(d_ws, 0, WS_HBUF_OFF, stream);

  void* args[] = { &h0, &c0, &Wih0, &Whh0, &bih0, &bhh0, &Wih1, &Whh1,
                   &bih1, &bhh1, &Wfc, &bfc, &outp, &wsp };
  hipError_t e = hipLaunchCooperativeKernel((const void*)decoder_kernel,
                                            dim3(NGROUP * GWG), dim3(NTHR),
                                            args, 0u, stream);
  if (e != hipSuccess) {
    // fallback: plain launch (256 full-CU blocks on 256 CUs are co-resident)
    decoder_kernel<<<dim3(NGROUP * GWG), dim3(NTHR), 0, stream>>>(
        h0, c0, Wih0, Whh0, bih0, bhh0, Wih1, Whh1, bih1, bhh1, Wfc, bfc, outp, wsp);
  }
}